// Round 16
// baseline (81.037 us; speedup 1.0000x reference)
//
#include <hip/hip_runtime.h>

// Problem constants
#define MM 15   // max_peptide_size
#define RR 64   // aa_rep_size
#define PP 34   // pocket positions
#define FF 9    // filter size
#define AA 20   // alphabet size
#define OW 72   // RR + FF - 1

// DPP controls (GFX9-family): whole-wave shift by one lane
#define WAVE_SHL1 0x130
#define WAVE_SHR1 0x138

// wave_shr1: result[lane] = src[lane-1], lane 0 -> 0 (bound_ctrl)
__device__ __forceinline__ float dpp_shr1(float x) {
    return __int_as_float(__builtin_amdgcn_update_dpp(
        0, __float_as_int(x), WAVE_SHR1, 0xF, 0xF, true));
}
// wave_shl1: result[lane] = src[lane+1], lane 63 -> 0 (bound_ctrl)
__device__ __forceinline__ float dpp_shl1(float x) {
    return __int_as_float(__builtin_amdgcn_update_dpp(
        0, __float_as_int(x), WAVE_SHL1, 0xF, 0xF, true));
}

// One block per sample, 4 independent waves, ZERO LDS, ZERO barriers.
// Wave w owns rows p = w + 4j. Lane = representation index r.
// Phase B: s[p][r] in register (gates via scalar loads).
// Phase C: 9-tap full conv via two DPP shift recurrences (pure VALU).
__global__ __launch_bounds__(256)
void ppc_kernel(const float* __restrict__ pe,      // [B, M, R]
                const int*   __restrict__ idx,     // [B, P]
                const int*   __restrict__ adj,     // [B, P, M]
                const float* __restrict__ kernels, // [A, F]
                float*       __restrict__ out)     // [B, P, OW]
{
    const int b    = blockIdx.x;
    const int lane = threadIdx.x & 63;
    const int w    = __builtin_amdgcn_readfirstlane(threadIdx.x >> 6);

    const float* peb  = pe  + (size_t)b * (MM * RR);
    const int*   adjb = adj + (size_t)b * (PP * MM);
    const int*   idxb = idx + (size_t)b * PP;
    float*       outb = out + (size_t)b * (PP * OW);

    // per-lane pe column (coalesced 256 B/wave; L1-shared across the 4 waves)
    float pv[MM];
    #pragma unroll
    for (int m = 0; m < MM; ++m) pv[m] = peb[m * RR + lane];

    #pragma unroll
    for (int j = 0; j < 9; ++j) {
        const int p = w + 4 * j;              // SGPR (w is readfirstlane'd)
        if (p < PP) {                         // wave-uniform branch
            // ---- Phase B: s = sum_m gate[m] * pv[m]; gates via SMEM loads
            const int* g = adjb + p * MM;     // uniform address -> s_load
            float s = 0.0f;
            #pragma unroll
            for (int m = 0; m < MM; ++m) {
                const float gf = g[m] ? 1.0f : 0.0f;   // s_cmp + s_cselect
                s = fmaf(gf, pv[m], s);
            }

            // ---- filter taps: wave-uniform scalar loads -> SGPRs
            const float* kb = kernels + idxb[p] * FF;
            float kf[FF];
            #pragma unroll
            for (int i2 = 0; i2 < FF; ++i2) kf[i2] = kb[i2];

            // ---- main outputs o = lane (0..63):
            // H[r] = sum_{i=0..8} kf[i] * s[r-i]   (s[<0] = 0 via bound_ctrl)
            float H = kf[8] * s;
            #pragma unroll
            for (int i2 = 7; i2 >= 0; --i2)
                H = fmaf(kf[i2], s, dpp_shr1(H));
            outb[p * OW + lane] = H;          // 256 B coalesced store

            // ---- tail outputs o = 64..71 (lanes 56..63, o = lane + 8):
            // T[r] = sum_{i=0..8} kf[i] * s[r+8-i] (s[>63] = 0 via bound_ctrl)
            float T = kf[0] * s;
            #pragma unroll
            for (int i2 = 1; i2 <= 8; ++i2)
                T = fmaf(kf[i2], s, dpp_shl1(T));
            if (lane >= 56)
                outb[p * OW + 8 + lane] = T;  // 32 B coalesced store
        }
    }
}

extern "C" void kernel_launch(void* const* d_in, const int* in_sizes, int n_in,
                              void* d_out, int out_size, void* d_ws, size_t ws_size,
                              hipStream_t stream) {
    const float* pe      = (const float*)d_in[0]; // [B,M,R] f32
    const int*   idx     = (const int*)  d_in[1]; // [B,P]   i32
    const int*   adj     = (const int*)  d_in[2]; // [B,P,M] i32
    const float* kernels = (const float*)d_in[3]; // [A,F]   f32
    float*       out     = (float*)d_out;

    const int B = in_sizes[0] / (MM * RR);
    ppc_kernel<<<B, 256, 0, stream>>>(pe, idx, adj, kernels, out);
}